// Round 9
// baseline (712.510 us; speedup 1.0000x reference)
//
#include <hip/hip_runtime.h>

#define CH      128
#define RBFD    200
#define NNODES  50000
#define NEDGES  600000
#define LOG2F_  0.6931471805599453f

// fragment-ordered weight blobs (bf16):
// w1F: 8 nt x 7 kt frags, each 64 lanes x 8 elems  -> 28672 elems
// w2F: 8 nt x 4 kt frags, each 64 lanes x 8 elems  -> 16384 elems
#define W1F_ELEMS (8 * 7 * 64 * 8)
#define W2F_ELEMS (8 * 4 * 64 * 8)
#define WF_TOT    (W1F_ELEMS + W2F_ELEMS)   // 45056

typedef __attribute__((ext_vector_type(8))) __bf16 bf16x8;
typedef __attribute__((ext_vector_type(4))) float  f32x4;

__device__ __forceinline__ float ssp(float x) {
    float e  = __expf(x);
    float sp = __logf(1.0f + e);
    sp = (x < 14.0f) ? sp : x;       // branchless guard (exp overflow discarded)
    return sp - LOG2F_;
}

__device__ __forceinline__ unsigned short f2bf(float f) {
    union { float f; unsigned int u; } v; v.f = f;
    unsigned int r = v.u + 0x7FFFu + ((v.u >> 16) & 1u);   // RNE
    return (unsigned short)(r >> 16);
}

__device__ __forceinline__ float bf2f(unsigned short s) {
    union { unsigned int u; float f; } v; v.u = ((unsigned int)s) << 16;
    return v.f;
}

__device__ __forceinline__ unsigned short cvt1bf(float f) {
    unsigned int u;
    asm("v_cvt_pk_bf16_f32 %0, %1, %2" : "=v"(u) : "v"(f), "v"(f));
    return (unsigned short)u;
}

__device__ __forceinline__ unsigned int cvt2bf(float lo, float hi) {
    unsigned int u;
    asm("v_cvt_pk_bf16_f32 %0, %1, %2" : "=v"(u) : "v"(lo), "v"(hi));
    return u;
}

// 8 consecutive fp32 -> bf16x8
__device__ __forceinline__ bf16x8 load_cvt8(const float* p) {
    float4 f0 = *(const float4*)p;
    float4 f1 = *(const float4*)(p + 4);
    union { unsigned int u[4]; bf16x8 v; } r;
    r.u[0] = cvt2bf(f0.x, f0.y);
    r.u[1] = cvt2bf(f0.z, f0.w);
    r.u[2] = cvt2bf(f1.x, f1.y);
    r.u[3] = cvt2bf(f1.z, f1.w);
    return r.v;
}

// ---- prep: w1/w2 in MFMA B-fragment order.
//      frag lane = l15 + 16*lg holds row (nt*16+l15), k-elems kt*32+lg*8 .. +8 ----
__global__ __launch_bounds__(256) void prep_weights_frag(const float* __restrict__ w1,
                                                         const float* __restrict__ w2,
                                                         unsigned short* __restrict__ w1F,
                                                         unsigned short* __restrict__ w2F) {
    int i = blockIdx.x * 256 + threadIdx.x;
    if (i < W1F_ELEMS) {
        int frag = i >> 9;              // /512
        int lane = (i >> 3) & 63;
        int j    = i & 7;
        int nt = frag / 7, kt = frag % 7;
        int n = nt * 16 + (lane & 15);
        int k = kt * 32 + (lane >> 4) * 8 + j;
        w1F[i] = (k < RBFD) ? f2bf(w1[k * CH + n]) : (unsigned short)0;
    } else if (i < WF_TOT) {
        int q = i - W1F_ELEMS;
        int frag = q >> 9;
        int lane = (q >> 3) & 63;
        int j    = q & 7;
        int nt = frag >> 2, kt = frag & 3;
        int n = nt * 16 + (lane & 15);
        int k = kt * 32 + (lane >> 4) * 8 + j;
        w2F[q] = f2bf(w2[k * CH + n]);
    }
}

// ---- CSR build (parallel scan) ----
__global__ __launch_bounds__(256) void k_hist(const int* __restrict__ src, int* __restrict__ cur) {
    int e = blockIdx.x * 256 + threadIdx.x;
    if (e < NEDGES) atomicAdd(&cur[src[e]], 1);
}

__global__ __launch_bounds__(256) void k_scan1(const int* __restrict__ cur, int* __restrict__ bsum) {
    __shared__ int s[256];
    const int t = threadIdx.x;
    int i = blockIdx.x * 256 + t;
    s[t] = (i < NNODES) ? cur[i] : 0;
    __syncthreads();
    for (int d = 128; d > 0; d >>= 1) {
        if (t < d) s[t] += s[t + d];
        __syncthreads();
    }
    if (t == 0) bsum[blockIdx.x] = s[0];
}

__global__ __launch_bounds__(256) void k_scan2(const int* __restrict__ bsum, int* __restrict__ bpre) {
    __shared__ int s[256];
    const int t = threadIdx.x;
    int v0 = (t < 196) ? bsum[t] : 0;
    s[t] = v0;
    __syncthreads();
    for (int d = 1; d < 256; d <<= 1) {
        int v = (t >= d) ? s[t - d] : 0;
        __syncthreads();
        s[t] += v;
        __syncthreads();
    }
    if (t < 196) bpre[t] = s[t] - v0;   // exclusive
}

__global__ __launch_bounds__(256) void k_scan3(const int* __restrict__ deg_in,
                                               const int* __restrict__ bpre,
                                               int* __restrict__ csr_off,
                                               int* __restrict__ cur) {
    __shared__ int s[256];
    const int t = threadIdx.x, b = blockIdx.x;
    const int i = b * 256 + t;
    int d0 = (i < NNODES) ? deg_in[i] : 0;
    s[t] = d0;
    __syncthreads();
    for (int d = 1; d < 256; d <<= 1) {
        int v = (t >= d) ? s[t - d] : 0;
        __syncthreads();
        s[t] += v;
        __syncthreads();
    }
    if (i < NNODES) {
        int ex = bpre[b] + s[t] - d0;
        csr_off[i] = ex;
        cur[i] = ex;
    }
    if (i == NNODES - 1) csr_off[NNODES] = NEDGES;
}

__global__ __launch_bounds__(256) void k_fill(const int* __restrict__ src,
                                              int* __restrict__ cur,
                                              int* __restrict__ eidx) {
    int e = blockIdx.x * 256 + threadIdx.x;
    if (e < NEDGES) {
        int pos = atomicAdd(&cur[src[e]], 1);
        eidx[pos] = e;
    }
}

// ---- edge pipeline v6: 16 edges/wave, kt-outer, small state, 8 waves/SIMD.
//      w = ssp(ssp(rbf@w1+b1)@w2+b2) -> wbuf[E][128] bf16 ----
__global__ __launch_bounds__(256, 8) void edge_kernel6(const float* __restrict__ rbf,
                                                       const float* __restrict__ b1v,
                                                       const float* __restrict__ b2v,
                                                       const unsigned short* __restrict__ w1F,
                                                       const unsigned short* __restrict__ w2F,
                                                       unsigned short* __restrict__ wbuf) {
    __shared__ unsigned short tile[4][16 * 128];   // 4 KB per wave, XOR-swizzled
    const int t = threadIdx.x;
    const int lane = t & 63;
    const int wv = t >> 6;
    const int l15 = lane & 15;
    const int lg  = lane >> 4;
    const size_t e0 = ((size_t)blockIdx.x * 4 + wv) * 16;
    char* myb = (char*)tile[wv];

    const bf16x8* w1v = (const bf16x8*)w1F;
    const bf16x8* w2v = (const bf16x8*)w2F;
    const float* arow = rbf + (e0 + l15) * RBFD;

    f32x4 acc[8];
#pragma unroll
    for (int nt = 0; nt < 8; nt++) acc[nt] = (f32x4){0.f, 0.f, 0.f, 0.f};

    // GEMM1: kt-outer, one A-frag live at a time
#pragma unroll
    for (int kt = 0; kt < 7; kt++) {
        bf16x8 a;
        if (kt < 6) {
            a = load_cvt8(arow + kt * 32 + lg * 8);
        } else if (lg == 0) {
            a = load_cvt8(arow + 192);
        } else {
            union { unsigned int u[4]; bf16x8 v; } z;
            z.u[0] = z.u[1] = z.u[2] = z.u[3] = 0;
            a = z.v;
        }
#pragma unroll
        for (int nt = 0; nt < 8; nt++)
            acc[nt] = __builtin_amdgcn_mfma_f32_16x16x32_bf16(a, w1v[((nt * 7 + kt) << 6) + lane],
                                                              acc[nt], 0, 0, 0);
    }

    const int myrow0 = lg * 4;                     // C/D: row=(lane>>4)*4+r, col=l15(+16nt)
#pragma unroll
    for (int nt = 0; nt < 8; nt++) {
        const float bias = b1v[nt * 16 + l15];
#pragma unroll
        for (int r = 0; r < 4; r++) {
            const int row = myrow0 + r;
            const int colb = (nt * 32 + l15 * 2) ^ ((row & 7) << 4);
            *(unsigned short*)(myb + row * 256 + colb) = cvt1bf(ssp(acc[nt][r] + bias));
        }
    }

    // A2 frags from swizzled LDS (read all before epilogue2 overwrites)
    bf16x8 a2[4];
#pragma unroll
    for (int kt = 0; kt < 4; kt++) {
        const int boff = l15 * 256 + ((kt * 64 + lg * 16) ^ ((l15 & 7) << 4));
        a2[kt] = *(const bf16x8*)(myb + boff);
    }

#pragma unroll
    for (int nt = 0; nt < 8; nt++) acc[nt] = (f32x4){0.f, 0.f, 0.f, 0.f};
#pragma unroll
    for (int kt = 0; kt < 4; kt++) {
#pragma unroll
        for (int nt = 0; nt < 8; nt++)
            acc[nt] = __builtin_amdgcn_mfma_f32_16x16x32_bf16(a2[kt], w2v[((nt * 4 + kt) << 6) + lane],
                                                              acc[nt], 0, 0, 0);
    }

#pragma unroll
    for (int nt = 0; nt < 8; nt++) {
        const float bias = b2v[nt * 16 + l15];
#pragma unroll
        for (int r = 0; r < 4; r++) {
            const int row = myrow0 + r;
            const int colb = (nt * 32 + l15 * 2) ^ ((row & 7) << 4);
            *(unsigned short*)(myb + row * 256 + colb) = cvt1bf(ssp(acc[nt][r] + bias));
        }
    }

    // copy-out: coalesced 16 rows x 256 B
    {
        const int row = lane >> 2, q = lane & 3;
        float4 o[4];
#pragma unroll
        for (int j = 0; j < 4; j++) {
            const int boff = row * 256 + ((q * 64 + j * 16) ^ ((row & 7) << 4));
            o[j] = *(const float4*)(myb + boff);
        }
        float4* gdst = (float4*)((char*)wbuf + (e0 + row) * 256 + q * 64);
#pragma unroll
        for (int j = 0; j < 4; j++) gdst[j] = o[j];
    }
}

// ---- node side (fp32, known-good): f=x@w3; conv = f * gather-sum(wbuf);
//      y=ssp(conv@w4+b4); out = x + y@w5 + b5 ----
__global__ __launch_bounds__(256) void node_gather2(const float* __restrict__ x,
                                                    const float* __restrict__ w3,
                                                    const float* __restrict__ w4,
                                                    const float* __restrict__ b4,
                                                    const float* __restrict__ w5,
                                                    const float* __restrict__ b5,
                                                    const unsigned short* __restrict__ wbuf,
                                                    const int* __restrict__ eidx,
                                                    const int* __restrict__ csr_off,
                                                    float* __restrict__ out,
                                                    int n_nodes) {
    __shared__ float A[32 * 128];
    __shared__ float B[32 * 128];
    const int t = threadIdx.x;
    const int n0 = blockIdx.x * 32;
    const int rows = min(32, n_nodes - n0);

    {   // stage x tile
        const float4* g = (const float4*)(x + (size_t)n0 * CH);
        float4* s = (float4*)A;
        for (int i = t; i < rows * 32; i += 256) s[i] = g[i];
    }
    __syncthreads();

    const int c = t & 127, eh = t >> 7;
    float acc[16];

    // f = x @ w3 -> B
#pragma unroll
    for (int i = 0; i < 16; i++) acc[i] = 0.f;
    for (int k = 0; k < 128; k += 4) {
        const float wa = w3[(k + 0) * CH + c];
        const float wb = w3[(k + 1) * CH + c];
        const float wc = w3[(k + 2) * CH + c];
        const float wd = w3[(k + 3) * CH + c];
#pragma unroll
        for (int i = 0; i < 16; i++) {
            const float4 v = *(const float4*)&A[(eh * 16 + i) * CH + k];
            acc[i] = fmaf(v.x, wa, acc[i]);
            acc[i] = fmaf(v.y, wb, acc[i]);
            acc[i] = fmaf(v.z, wc, acc[i]);
            acc[i] = fmaf(v.w, wd, acc[i]);
        }
    }
#pragma unroll
    for (int i = 0; i < 16; i++) B[(eh * 16 + i) * 128 + c] = acc[i];
    __syncthreads();

    // gather: wave wv handles nodes [wv*8, wv*8+8); lane covers ch 2l,2l+1
    {
        const int lane = t & 63, wv = t >> 6;
        const int c0 = lane * 2;
        for (int rr = 0; rr < 8; rr++) {
            const int r = wv * 8 + rr;
            const int n = n0 + r;
            float s0 = 0.f, s1 = 0.f;
            if (n < n_nodes) {
                const int o0 = csr_off[n], o1 = csr_off[n + 1];
                int j = o0;
                for (; j + 3 < o1; j += 4) {
                    const int ea = eidx[j], eb = eidx[j + 1], ec = eidx[j + 2], ed = eidx[j + 3];
                    const unsigned ua = *(const unsigned*)(wbuf + (size_t)ea * CH + c0);
                    const unsigned ub = *(const unsigned*)(wbuf + (size_t)eb * CH + c0);
                    const unsigned uc = *(const unsigned*)(wbuf + (size_t)ec * CH + c0);
                    const unsigned ud = *(const unsigned*)(wbuf + (size_t)ed * CH + c0);
                    s0 += bf2f((unsigned short)ua) + bf2f((unsigned short)ub)
                        + bf2f((unsigned short)uc) + bf2f((unsigned short)ud);
                    s1 += bf2f((unsigned short)(ua >> 16)) + bf2f((unsigned short)(ub >> 16))
                        + bf2f((unsigned short)(uc >> 16)) + bf2f((unsigned short)(ud >> 16));
                }
                for (; j < o1; j++) {
                    const unsigned ua = *(const unsigned*)(wbuf + (size_t)eidx[j] * CH + c0);
                    s0 += bf2f((unsigned short)ua);
                    s1 += bf2f((unsigned short)(ua >> 16));
                }
            }
            const float2 f2 = *(const float2*)&B[r * 128 + c0];
            float2 v2;
            v2.x = (n < n_nodes) ? f2.x * s0 : 0.f;
            v2.y = (n < n_nodes) ? f2.y * s1 : 0.f;
            *(float2*)&B[r * 128 + c0] = v2;
        }
    }
    __syncthreads();

    // y = ssp(B @ w4 + b4) -> A
#pragma unroll
    for (int i = 0; i < 16; i++) acc[i] = 0.f;
    for (int k = 0; k < 128; k += 4) {
        const float wa = w4[(k + 0) * CH + c];
        const float wb = w4[(k + 1) * CH + c];
        const float wc = w4[(k + 2) * CH + c];
        const float wd = w4[(k + 3) * CH + c];
#pragma unroll
        for (int i = 0; i < 16; i++) {
            const float4 v = *(const float4*)&B[(eh * 16 + i) * CH + k];
            acc[i] = fmaf(v.x, wa, acc[i]);
            acc[i] = fmaf(v.y, wb, acc[i]);
            acc[i] = fmaf(v.z, wc, acc[i]);
            acc[i] = fmaf(v.w, wd, acc[i]);
        }
    }
    {
        const float bias4 = b4[c];
#pragma unroll
        for (int i = 0; i < 16; i++)
            A[(eh * 16 + i) * 128 + c] = ssp(acc[i] + bias4);
    }
    __syncthreads();

    // v = A @ w5 + b5 ; out = x + v
#pragma unroll
    for (int i = 0; i < 16; i++) acc[i] = 0.f;
    for (int k = 0; k < 128; k += 4) {
        const float wa = w5[(k + 0) * CH + c];
        const float wb = w5[(k + 1) * CH + c];
        const float wc = w5[(k + 2) * CH + c];
        const float wd = w5[(k + 3) * CH + c];
#pragma unroll
        for (int i = 0; i < 16; i++) {
            const float4 v = *(const float4*)&A[(eh * 16 + i) * CH + k];
            acc[i] = fmaf(v.x, wa, acc[i]);
            acc[i] = fmaf(v.y, wb, acc[i]);
            acc[i] = fmaf(v.z, wc, acc[i]);
            acc[i] = fmaf(v.w, wd, acc[i]);
        }
    }
    {
        const float bias5 = b5[c];
#pragma unroll
        for (int i = 0; i < 16; i++) {
            const int r = eh * 16 + i;
            if (r < rows) {
                const size_t off = ((size_t)(n0 + r)) * CH + c;
                out[off] = x[off] + acc[i] + bias5;
            }
        }
    }
}

static inline size_t align_up(size_t v, size_t a) { return (v + a - 1) & ~(a - 1); }

extern "C" void kernel_launch(void* const* d_in, const int* in_sizes, int n_in,
                              void* d_out, int out_size, void* d_ws, size_t ws_size,
                              hipStream_t stream) {
    const float* rbf = (const float*)d_in[0];
    const float* x   = (const float*)d_in[1];
    const int*   src = (const int*)d_in[2];
    const float* w1  = (const float*)d_in[3];
    const float* b1  = (const float*)d_in[4];
    const float* w2  = (const float*)d_in[5];
    const float* b2  = (const float*)d_in[6];
    const float* w3  = (const float*)d_in[7];
    const float* w4  = (const float*)d_in[8];
    const float* b4  = (const float*)d_in[9];
    const float* w5  = (const float*)d_in[10];
    const float* b5  = (const float*)d_in[11];

    float* out = (float*)d_out;

    size_t off = 0;
    const size_t o_wbuf = off;  off = align_up(off + (size_t)NEDGES * CH * 2, 256);
    const size_t o_eidx = off;  off = align_up(off + (size_t)NEDGES * 4, 256);
    const size_t o_csr  = off;  off = align_up(off + (size_t)(NNODES + 1) * 4, 256);
    const size_t o_cur  = off;  off = align_up(off + (size_t)NNODES * 4, 256);
    const size_t o_bs   = off;  off = align_up(off + 256 * 4, 256);
    const size_t o_bp   = off;  off = align_up(off + 256 * 4, 256);
    const size_t o_wF   = off;  off = align_up(off + (size_t)WF_TOT * 2, 256);

    unsigned short* wbuf = (unsigned short*)((char*)d_ws + o_wbuf);
    int* eidx            = (int*)((char*)d_ws + o_eidx);
    int* csr_off         = (int*)((char*)d_ws + o_csr);
    int* cur             = (int*)((char*)d_ws + o_cur);
    int* bsum            = (int*)((char*)d_ws + o_bs);
    int* bpre            = (int*)((char*)d_ws + o_bp);
    unsigned short* w1F  = (unsigned short*)((char*)d_ws + o_wF);
    unsigned short* w2F  = w1F + W1F_ELEMS;

    hipMemsetAsync(cur, 0, (size_t)NNODES * 4, stream);
    prep_weights_frag<<<(WF_TOT + 255) / 256, 256, 0, stream>>>(w1, w2, w1F, w2F);
    // 37500 wave-jobs of 16 edges; 4 waves/block
    edge_kernel6<<<37500 / 4, 256, 0, stream>>>(rbf, b1, b2, w1F, w2F, wbuf);
    k_hist<<<(NEDGES + 255) / 256, 256, 0, stream>>>(src, cur);
    k_scan1<<<196, 256, 0, stream>>>(cur, bsum);
    k_scan2<<<1, 256, 0, stream>>>(bsum, bpre);
    k_scan3<<<196, 256, 0, stream>>>(cur, bpre, csr_off, cur);
    k_fill<<<(NEDGES + 255) / 256, 256, 0, stream>>>(src, cur, eidx);
    node_gather2<<<(NNODES + 31) / 32, 256, 0, stream>>>(x, w3, w4, b4, w5, b5,
                                                         wbuf, eidx, csr_off, out, NNODES);
}

// Round 11
// 492.143 us; speedup vs baseline: 1.4478x; 1.4478x over previous
//
#include <hip/hip_runtime.h>

#define CH      128
#define RBFD    200
#define NNODES  50000
#define NEDGES  600000
#define LOG2F_  0.6931471805599453f
#define RSTR    232     // rbf_s row stride (bf16): 464 B -> odd 16B-granule stride, 2-way max
#define HSTR    136     // h_s/w_s row stride (bf16): 272 B

// fragment-ordered weight blobs (bf16):
// w1F: 8 nt x 7 kt frags, each 64 lanes x 8 elems  -> 28672 elems
// w2F: 8 nt x 4 kt frags, each 64 lanes x 8 elems  -> 16384 elems
#define W1F_ELEMS (8 * 7 * 64 * 8)
#define W2F_ELEMS (8 * 4 * 64 * 8)
#define WF_TOT    (W1F_ELEMS + W2F_ELEMS)   // 45056

typedef __attribute__((ext_vector_type(8))) __bf16 bf16x8;
typedef __attribute__((ext_vector_type(4))) float  f32x4;

__device__ __forceinline__ float ssp(float x) {
    float e  = __expf(x);
    float sp = __logf(1.0f + e);
    sp = (x < 14.0f) ? sp : x;       // branchless guard (exp overflow discarded)
    return sp - LOG2F_;
}

__device__ __forceinline__ unsigned short f2bf(float f) {
    union { float f; unsigned int u; } v; v.f = f;
    unsigned int r = v.u + 0x7FFFu + ((v.u >> 16) & 1u);   // RNE
    return (unsigned short)(r >> 16);
}

__device__ __forceinline__ float bf2f(unsigned short s) {
    union { unsigned int u; float f; } v; v.u = ((unsigned int)s) << 16;
    return v.f;
}

__device__ __forceinline__ unsigned short cvt1bf(float f) {
    unsigned int u;
    asm("v_cvt_pk_bf16_f32 %0, %1, %2" : "=v"(u) : "v"(f), "v"(f));
    return (unsigned short)u;
}

__device__ __forceinline__ unsigned int cvt2bf(float lo, float hi) {
    unsigned int u;
    asm("v_cvt_pk_bf16_f32 %0, %1, %2" : "=v"(u) : "v"(lo), "v"(hi));
    return u;
}

// ---- prep: w1/w2 in MFMA B-fragment order ----
__global__ __launch_bounds__(256) void prep_weights_frag(const float* __restrict__ w1,
                                                         const float* __restrict__ w2,
                                                         unsigned short* __restrict__ w1F,
                                                         unsigned short* __restrict__ w2F) {
    int i = blockIdx.x * 256 + threadIdx.x;
    if (i < W1F_ELEMS) {
        int frag = i >> 9;
        int lane = (i >> 3) & 63;
        int j    = i & 7;
        int nt = frag / 7, kt = frag % 7;
        int n = nt * 16 + (lane & 15);
        int k = kt * 32 + (lane >> 4) * 8 + j;
        w1F[i] = (k < RBFD) ? f2bf(w1[k * CH + n]) : (unsigned short)0;
    } else if (i < WF_TOT) {
        int q = i - W1F_ELEMS;
        int frag = q >> 9;
        int lane = (q >> 3) & 63;
        int j    = q & 7;
        int nt = frag >> 2, kt = frag & 3;
        int n = nt * 16 + (lane & 15);
        int k = kt * 32 + (lane >> 4) * 8 + j;
        w2F[q] = f2bf(w2[k * CH + n]);
    }
}

// ---- CSR build (parallel scan) ----
__global__ __launch_bounds__(256) void k_hist(const int* __restrict__ src, int* __restrict__ cur) {
    int e = blockIdx.x * 256 + threadIdx.x;
    if (e < NEDGES) atomicAdd(&cur[src[e]], 1);
}

__global__ __launch_bounds__(256) void k_scan1(const int* __restrict__ cur, int* __restrict__ bsum) {
    __shared__ int s[256];
    const int t = threadIdx.x;
    int i = blockIdx.x * 256 + t;
    s[t] = (i < NNODES) ? cur[i] : 0;
    __syncthreads();
    for (int d = 128; d > 0; d >>= 1) {
        if (t < d) s[t] += s[t + d];
        __syncthreads();
    }
    if (t == 0) bsum[blockIdx.x] = s[0];
}

__global__ __launch_bounds__(256) void k_scan2(const int* __restrict__ bsum, int* __restrict__ bpre) {
    __shared__ int s[256];
    const int t = threadIdx.x;
    int v0 = (t < 196) ? bsum[t] : 0;
    s[t] = v0;
    __syncthreads();
    for (int d = 1; d < 256; d <<= 1) {
        int v = (t >= d) ? s[t - d] : 0;
        __syncthreads();
        s[t] += v;
        __syncthreads();
    }
    if (t < 196) bpre[t] = s[t] - v0;   // exclusive
}

__global__ __launch_bounds__(256) void k_scan3(const int* __restrict__ deg_in,
                                               const int* __restrict__ bpre,
                                               int* __restrict__ csr_off,
                                               int* __restrict__ cur) {
    __shared__ int s[256];
    const int t = threadIdx.x, b = blockIdx.x;
    const int i = b * 256 + t;
    int d0 = (i < NNODES) ? deg_in[i] : 0;
    s[t] = d0;
    __syncthreads();
    for (int d = 1; d < 256; d <<= 1) {
        int v = (t >= d) ? s[t - d] : 0;
        __syncthreads();
        s[t] += v;
        __syncthreads();
    }
    if (i < NNODES) {
        int ex = bpre[b] + s[t] - d0;
        csr_off[i] = ex;
        cur[i] = ex;
    }
    if (i == NNODES - 1) csr_off[NNODES] = NEDGES;
}

__global__ __launch_bounds__(256) void k_fill(const int* __restrict__ src,
                                              int* __restrict__ cur,
                                              int* __restrict__ eidx) {
    int e = blockIdx.x * 256 + threadIdx.x;
    if (e < NEDGES) {
        int pos = atomicAdd(&cur[src[e]], 1);
        eidx[pos] = e;
    }
}

// ---- edge pipeline v7: 32-edge block-cooperative, shared rbf staging,
//      small per-wave state (no launch_bounds min-wave pressure), 6 blocks/CU.
//      w = ssp(ssp(rbf@w1+b1)@w2+b2) -> wbuf[E][128] bf16 ----
__global__ __launch_bounds__(256) void edge_kernel7(const float* __restrict__ rbf,
                                                    const float* __restrict__ b1v,
                                                    const float* __restrict__ b2v,
                                                    const unsigned short* __restrict__ w1F,
                                                    const unsigned short* __restrict__ w2F,
                                                    unsigned short* __restrict__ wbuf) {
    __shared__ unsigned short rbf_s[32 * RSTR];   // 14848 B, reused as w_s after GEMM1
    __shared__ unsigned short h_s[32 * HSTR];     // 8704 B         (total 23552 B)
    unsigned short* w_s = rbf_s;
    const int t = threadIdx.x;
    const int lane = t & 63;
    const int wv = t >> 6;
    const int l15 = lane & 15;
    const int lg  = lane >> 4;
    const size_t e0 = (size_t)blockIdx.x * 32;

    const bf16x8* w1v = (const bf16x8*)w1F;
    const bf16x8* w2v = (const bf16x8*)w2F;

    // ---- stage rbf tile [32][200] fp32 -> bf16 (1-instr packed cvt), pad to 224 ----
    {
        const float4* g = (const float4*)(rbf + e0 * RBFD);
        for (int i = t; i < 1600; i += 256) {
            float4 v = g[i];
            int row = i / 50, c4 = (i % 50) * 4;
            union { unsigned int u[2]; unsigned long long ull; } p;
            p.u[0] = cvt2bf(v.x, v.y);
            p.u[1] = cvt2bf(v.z, v.w);
            *(unsigned long long*)&rbf_s[row * RSTR + c4] = p.ull;
        }
        for (int i = t; i < 768; i += 256) {
            int row = i / 24, k = RBFD + (i % 24);
            rbf_s[row * RSTR + k] = 0;
        }
    }
    __syncthreads();

    const float bias10 = b1v[wv * 32 + l15];
    const float bias11 = b1v[wv * 32 + 16 + l15];
    const int myrow0 = lg * 4;                    // C/D: row=(lane>>4)*4+r, col=l15(+16nt)

    // ---- GEMM1: wave owns cols [wv*32, wv*32+32); m-loop over 16-edge strips ----
#pragma unroll
    for (int m = 0; m < 2; m++) {
        f32x4 acc0 = {0.f, 0.f, 0.f, 0.f};
        f32x4 acc1 = {0.f, 0.f, 0.f, 0.f};
        const unsigned short* abase = &rbf_s[(m * 16 + l15) * RSTR + lg * 8];
        const int nt0 = wv * 2, nt1 = wv * 2 + 1;
#pragma unroll
        for (int kt = 0; kt < 7; kt++) {
            bf16x8 a = *(const bf16x8*)(abase + kt * 32);
            acc0 = __builtin_amdgcn_mfma_f32_16x16x32_bf16(a, w1v[((nt0 * 7 + kt) << 6) + lane], acc0, 0, 0, 0);
            acc1 = __builtin_amdgcn_mfma_f32_16x16x32_bf16(a, w1v[((nt1 * 7 + kt) << 6) + lane], acc1, 0, 0, 0);
        }
        const int hrow0 = m * 16 + myrow0;
#pragma unroll
        for (int r = 0; r < 4; r++) {
            h_s[(hrow0 + r) * HSTR + wv * 32 + l15]      = cvt1bf(ssp(acc0[r] + bias10));
            h_s[(hrow0 + r) * HSTR + wv * 32 + 16 + l15] = cvt1bf(ssp(acc1[r] + bias11));
        }
    }
    __syncthreads();   // h complete; rbf_s now dead -> w_s

    const float bias20 = b2v[wv * 32 + l15];
    const float bias21 = b2v[wv * 32 + 16 + l15];

    // ---- GEMM2: w = ssp(h @ w2 + b2) -> w_s ----
#pragma unroll
    for (int m = 0; m < 2; m++) {
        f32x4 acc0 = {0.f, 0.f, 0.f, 0.f};
        f32x4 acc1 = {0.f, 0.f, 0.f, 0.f};
        const unsigned short* abase = &h_s[(m * 16 + l15) * HSTR + lg * 8];
        const int nt0 = wv * 2, nt1 = wv * 2 + 1;
#pragma unroll
        for (int kt = 0; kt < 4; kt++) {
            bf16x8 a = *(const bf16x8*)(abase + kt * 32);
            acc0 = __builtin_amdgcn_mfma_f32_16x16x32_bf16(a, w2v[((nt0 * 4 + kt) << 6) + lane], acc0, 0, 0, 0);
            acc1 = __builtin_amdgcn_mfma_f32_16x16x32_bf16(a, w2v[((nt1 * 4 + kt) << 6) + lane], acc1, 0, 0, 0);
        }
        const int wrow0 = m * 16 + myrow0;
#pragma unroll
        for (int r = 0; r < 4; r++) {
            w_s[(wrow0 + r) * HSTR + wv * 32 + l15]      = cvt1bf(ssp(acc0[r] + bias20));
            w_s[(wrow0 + r) * HSTR + wv * 32 + 16 + l15] = cvt1bf(ssp(acc1[r] + bias21));
        }
    }
    __syncthreads();

    // ---- cooperative coalesced copy-out: 32 rows x 128 bf16 = 512 float4 ----
    for (int i = t; i < 512; i += 256) {
        const int row = i >> 4, q = i & 15;
        float4 v = *(const float4*)&w_s[row * HSTR + q * 8];
        ((float4*)wbuf)[(e0 + row) * 16 + q] = v;
    }
}

// ---- node side (fp32, known-good): f=x@w3; conv = f * gather-sum(wbuf);
//      y=ssp(conv@w4+b4); out = x + y@w5 + b5 ----
__global__ __launch_bounds__(256) void node_gather2(const float* __restrict__ x,
                                                    const float* __restrict__ w3,
                                                    const float* __restrict__ w4,
                                                    const float* __restrict__ b4,
                                                    const float* __restrict__ w5,
                                                    const float* __restrict__ b5,
                                                    const unsigned short* __restrict__ wbuf,
                                                    const int* __restrict__ eidx,
                                                    const int* __restrict__ csr_off,
                                                    float* __restrict__ out,
                                                    int n_nodes) {
    __shared__ float A[32 * 128];
    __shared__ float B[32 * 128];
    const int t = threadIdx.x;
    const int n0 = blockIdx.x * 32;
    const int rows = min(32, n_nodes - n0);

    {   // stage x tile
        const float4* g = (const float4*)(x + (size_t)n0 * CH);
        float4* s = (float4*)A;
        for (int i = t; i < rows * 32; i += 256) s[i] = g[i];
    }
    __syncthreads();

    const int c = t & 127, eh = t >> 7;
    float acc[16];

    // f = x @ w3 -> B
#pragma unroll
    for (int i = 0; i < 16; i++) acc[i] = 0.f;
    for (int k = 0; k < 128; k += 4) {
        const float wa = w3[(k + 0) * CH + c];
        const float wb = w3[(k + 1) * CH + c];
        const float wc = w3[(k + 2) * CH + c];
        const float wd = w3[(k + 3) * CH + c];
#pragma unroll
        for (int i = 0; i < 16; i++) {
            const float4 v = *(const float4*)&A[(eh * 16 + i) * CH + k];
            acc[i] = fmaf(v.x, wa, acc[i]);
            acc[i] = fmaf(v.y, wb, acc[i]);
            acc[i] = fmaf(v.z, wc, acc[i]);
            acc[i] = fmaf(v.w, wd, acc[i]);
        }
    }
#pragma unroll
    for (int i = 0; i < 16; i++) B[(eh * 16 + i) * 128 + c] = acc[i];
    __syncthreads();

    // gather: wave wv handles nodes [wv*8, wv*8+8); lane covers ch 2l,2l+1
    {
        const int lane = t & 63, wv = t >> 6;
        const int c0 = lane * 2;
        for (int rr = 0; rr < 8; rr++) {
            const int r = wv * 8 + rr;
            const int n = n0 + r;
            float s0 = 0.f, s1 = 0.f;
            if (n < n_nodes) {
                const int o0 = csr_off[n], o1 = csr_off[n + 1];
                int j = o0;
                for (; j + 3 < o1; j += 4) {
                    const int ea = eidx[j], eb = eidx[j + 1], ec = eidx[j + 2], ed = eidx[j + 3];
                    const unsigned ua = *(const unsigned*)(wbuf + (size_t)ea * CH + c0);
                    const unsigned ub = *(const unsigned*)(wbuf + (size_t)eb * CH + c0);
                    const unsigned uc = *(const unsigned*)(wbuf + (size_t)ec * CH + c0);
                    const unsigned ud = *(const unsigned*)(wbuf + (size_t)ed * CH + c0);
                    s0 += bf2f((unsigned short)ua) + bf2f((unsigned short)ub)
                        + bf2f((unsigned short)uc) + bf2f((unsigned short)ud);
                    s1 += bf2f((unsigned short)(ua >> 16)) + bf2f((unsigned short)(ub >> 16))
                        + bf2f((unsigned short)(uc >> 16)) + bf2f((unsigned short)(ud >> 16));
                }
                for (; j < o1; j++) {
                    const unsigned ua = *(const unsigned*)(wbuf + (size_t)eidx[j] * CH + c0);
                    s0 += bf2f((unsigned short)ua);
                    s1 += bf2f((unsigned short)(ua >> 16));
                }
            }
            const float2 f2 = *(const float2*)&B[r * 128 + c0];
            float2 v2;
            v2.x = (n < n_nodes) ? f2.x * s0 : 0.f;
            v2.y = (n < n_nodes) ? f2.y * s1 : 0.f;
            *(float2*)&B[r * 128 + c0] = v2;
        }
    }
    __syncthreads();

    // y = ssp(B @ w4 + b4) -> A
#pragma unroll
    for (int i = 0; i < 16; i++) acc[i] = 0.f;
    for (int k = 0; k < 128; k += 4) {
        const float wa = w4[(k + 0) * CH + c];
        const float wb = w4[(k + 1) * CH + c];
        const float wc = w4[(k + 2) * CH + c];
        const float wd = w4[(k + 3) * CH + c];
#pragma unroll
        for (int i = 0; i < 16; i++) {
            const float4 v = *(const float4*)&B[(eh * 16 + i) * CH + k];
            acc[i] = fmaf(v.x, wa, acc[i]);
            acc[i] = fmaf(v.y, wb, acc[i]);
            acc[i] = fmaf(v.z, wc, acc[i]);
            acc[i] = fmaf(v.w, wd, acc[i]);
        }
    }
    {
        const float bias4 = b4[c];
#pragma unroll
        for (int i = 0; i < 16; i++)
            A[(eh * 16 + i) * 128 + c] = ssp(acc[i] + bias4);
    }
    __syncthreads();

    // v = A @ w5 + b5 ; out = x + v
#pragma unroll
    for (int i = 0; i < 16; i++) acc[i] = 0.f;
    for (int k = 0; k < 128; k += 4) {
        const float wa = w5[(k + 0) * CH + c];
        const float wb = w5[(k + 1) * CH + c];
        const float wc = w5[(k + 2) * CH + c];
        const float wd = w5[(k + 3) * CH + c];
#pragma unroll
        for (int i = 0; i < 16; i++) {
            const float4 v = *(const float4*)&A[(eh * 16 + i) * CH + k];
            acc[i] = fmaf(v.x, wa, acc[i]);
            acc[i] = fmaf(v.y, wb, acc[i]);
            acc[i] = fmaf(v.z, wc, acc[i]);
            acc[i] = fmaf(v.w, wd, acc[i]);
        }
    }
    {
        const float bias5 = b5[c];
#pragma unroll
        for (int i = 0; i < 16; i++) {
            const int r = eh * 16 + i;
            if (r < rows) {
                const size_t off = ((size_t)(n0 + r)) * CH + c;
                out[off] = x[off] + acc[i] + bias5;
            }
        }
    }
}

static inline size_t align_up(size_t v, size_t a) { return (v + a - 1) & ~(a - 1); }

extern "C" void kernel_launch(void* const* d_in, const int* in_sizes, int n_in,
                              void* d_out, int out_size, void* d_ws, size_t ws_size,
                              hipStream_t stream) {
    const float* rbf = (const float*)d_in[0];
    const float* x   = (const float*)d_in[1];
    const int*   src = (const int*)d_in[2];
    const float* w1  = (const float*)d_in[3];
    const float* b1  = (const float*)d_in[4];
    const float* w2  = (const float*)d_in[5];
    const float* b2  = (const float*)d_in[6];
    const float* w3  = (const float*)d_in[7];
    const float* w4  = (const float*)d_in[8];
    const float* b4  = (const float*)d_in[9];
    const float* w5  = (const float*)d_in[10];
    const float* b5  = (const float*)d_in[11];

    float* out = (float*)d_out;

    size_t off = 0;
    const size_t o_wbuf = off;  off = align_up(off + (size_t)NEDGES * CH * 2, 256);
    const size_t o_eidx = off;  off = align_up(off + (size_t)NEDGES * 4, 256);
    const size_t o_csr  = off;  off = align_up(off + (size_t)(NNODES + 1) * 4, 256);
    const size_t o_cur  = off;  off = align_up(off + (size_t)NNODES * 4, 256);
    const size_t o_bs   = off;  off = align_up(off + 256 * 4, 256);
    const size_t o_bp   = off;  off = align_up(off + 256 * 4, 256);
    const size_t o_wF   = off;  off = align_up(off + (size_t)WF_TOT * 2, 256);

    unsigned short* wbuf = (unsigned short*)((char*)d_ws + o_wbuf);
    int* eidx            = (int*)((char*)d_ws + o_eidx);
    int* csr_off         = (int*)((char*)d_ws + o_csr);
    int* cur             = (int*)((char*)d_ws + o_cur);
    int* bsum            = (int*)((char*)d_ws + o_bs);
    int* bpre            = (int*)((char*)d_ws + o_bp);
    unsigned short* w1F  = (unsigned short*)((char*)d_ws + o_wF);
    unsigned short* w2F  = w1F + W1F_ELEMS;

    hipMemsetAsync(cur, 0, (size_t)NNODES * 4, stream);
    prep_weights_frag<<<(WF_TOT + 255) / 256, 256, 0, stream>>>(w1, w2, w1F, w2F);
    edge_kernel7<<<NEDGES / 32, 256, 0, stream>>>(rbf, b1, b2, w1F, w2F, wbuf);
    k_hist<<<(NEDGES + 255) / 256, 256, 0, stream>>>(src, cur);
    k_scan1<<<196, 256, 0, stream>>>(cur, bsum);
    k_scan2<<<1, 256, 0, stream>>>(bsum, bpre);
    k_scan3<<<196, 256, 0, stream>>>(cur, bpre, csr_off, cur);
    k_fill<<<(NEDGES + 255) / 256, 256, 0, stream>>>(src, cur, eidx);
    node_gather2<<<(NNODES + 31) / 32, 256, 0, stream>>>(x, w3, w4, b4, w5, b5,
                                                         wbuf, eidx, csr_off, out, NNODES);
}